// Round 1
// 339.831 us; speedup vs baseline: 1.1318x; 1.1318x over previous
//
#include <hip/hip_runtime.h>
#include <math.h>

// N=100000 nodes, E=1600000 edges, features 128 -> 64 -> 64 -> 1.
// R22 = R21 with the global-atomic histogram (k_hist, ~70us = 18% of total)
// replaced by an atomic-free two-pass counting sort:
//   k_cnt:     4 shards x 64 chunks; per-block LDS histogram (100KB) of the
//              chunk's dsts in the block's node shard; LDS atomicAdd returns
//              the edge's LOCAL rank (uchar); per-(chunk,shard) counts out.
//   k_blkscan: per node, exclusive prefix over the 64 chunk counts ->
//              in-place block offsets; total -> deg.
//   k_build_csr: pos = rowptr[d] + blkoff[chunk][d] + lrank[e].
// Rationale (R21 rocprof): k_hist had VALUBusy 0.24%, WRITE_SIZE 56MB for a
// 6.4MB store kernel -> ~32B memory-side RMW per atomic; 1.6M atomics ran at
// ~23G/s, an op-rate floor (68-72us across R15/R19/R20). LDS atomics stay
// on-CU. lrank aliases TSB, cnt aliases HB (dead before gemm1/agg write them).
// NOTE: __launch_bounds__(256,4) is 0-for-4 on this harness — do not use.
// gemm2 K-loop needs `#pragma unroll 2` (full unroll -> 256 VGPR, occ 9%).
#define NN 100000
#define NE 1600000
#define NSHARD 4
#define SHARD_W (NN / NSHARD)   // 25000 exactly
#define NCHUNK 64
#define CHUNK_E (NE / NCHUNK)   // 25000 edges per chunk
#define CHUNK_I4 (CHUNK_E / 4)  // 6250 int4 per chunk

// bf16 helpers (manual, round-to-nearest-even; intermediates only)
__device__ inline unsigned f2bf(float f) {
    unsigned u = __float_as_uint(f);
    u += 0x7FFFu + ((u >> 16) & 1u);
    return u >> 16;
}
__device__ inline float bflo(unsigned v) { return __uint_as_float(v << 16); }
__device__ inline float bfhi(unsigned v) { return __uint_as_float(v & 0xFFFF0000u); }

// ---------------------------------------------------------------------------
// CSR build: LDS counting-sort (no device-scope atomics).
// ---------------------------------------------------------------------------
// Pass A: block (shard s, chunk b) streams 25000 dsts of chunk b; dsts in
// [s*25000,(s+1)*25000) are histogrammed in a 100KB LDS uint array. The LDS
// atomicAdd's returned old value = the edge's rank among same-dst edges of
// this (chunk,shard) -> lrank (uchar; max degree ~45 << 255, Poisson(16)).
// Counts written byte-packed to cnt[b*NN + n].
__global__ __launch_bounds__(256) void k_cnt(const int4* __restrict__ dst4,
                                             unsigned char* __restrict__ cnt,
                                             unsigned char* __restrict__ lrank) {
    __shared__ __align__(16) unsigned ldeg[SHARD_W];  // 100 KB (gfx950: 160 KB/CU)
    int t = threadIdx.x;
    int shard = blockIdx.x & (NSHARD - 1);
    int b = blockIdx.x >> 2;
    int lo = shard * SHARD_W;
    for (int i = t; i < SHARD_W; i += 256) ldeg[i] = 0u;
    __syncthreads();
    const int4* p = dst4 + b * CHUNK_I4;
    unsigned char* lr = lrank + b * CHUNK_E;
#pragma unroll 4
    for (int j = t; j < CHUNK_I4; j += 256) {
        int4 d = p[j];
        unsigned ex = (unsigned)(d.x - lo);
        unsigned ey = (unsigned)(d.y - lo);
        unsigned ez = (unsigned)(d.z - lo);
        unsigned ew = (unsigned)(d.w - lo);
        if (ex < SHARD_W) lr[4 * j + 0] = (unsigned char)atomicAdd(&ldeg[ex], 1u);
        if (ey < SHARD_W) lr[4 * j + 1] = (unsigned char)atomicAdd(&ldeg[ey], 1u);
        if (ez < SHARD_W) lr[4 * j + 2] = (unsigned char)atomicAdd(&ldeg[ez], 1u);
        if (ew < SHARD_W) lr[4 * j + 3] = (unsigned char)atomicAdd(&ldeg[ew], 1u);
    }
    __syncthreads();
    unsigned* cb32 = (unsigned*)cnt + b * (NN / 4) + shard * (SHARD_W / 4);
    for (int i = t; i < SHARD_W / 4; i += 256) {
        uint4 v = *(const uint4*)&ldeg[4 * i];
        cb32[i] = (v.x & 255u) | ((v.y & 255u) << 8) | ((v.z & 255u) << 16)
                | ((v.w & 255u) << 24);
    }
}

// Pass B: per node, exclusive prefix across the 64 chunk counts (in place,
// byte-packed, 4 nodes/thread); row total -> deg. All loads issued up front
// (constant indices -> registers, ~64 VGPR; no scratch per rule #20).
__global__ __launch_bounds__(256) void k_blkscan(unsigned* __restrict__ cnt32,
                                                 int4* __restrict__ deg4) {
    int i = blockIdx.x * 256 + threadIdx.x;
    if (i >= NN / 4) return;
    unsigned c[NCHUNK];
#pragma unroll
    for (int b = 0; b < NCHUNK; ++b) c[b] = cnt32[b * (NN / 4) + i];
    unsigned a0 = 0, a1 = 0, a2 = 0, a3 = 0;
#pragma unroll
    for (int b = 0; b < NCHUNK; ++b) {
        unsigned v = c[b];
        cnt32[b * (NN / 4) + i] = a0 | (a1 << 8) | (a2 << 16) | (a3 << 24);
        a0 += v & 255u;
        a1 += (v >> 8) & 255u;
        a2 += (v >> 16) & 255u;
        a3 += v >> 24;
    }
    deg4[i] = make_int4((int)a0, (int)a1, (int)a2, (int)a3);
}

__global__ void k_bsum(const int* __restrict__ deg, int* __restrict__ bsums) {
    __shared__ int s[256];
    int t = threadIdx.x;
    int i = blockIdx.x * 256 + t;
    s[t] = (i < NN) ? deg[i] : 0;
    __syncthreads();
    for (int off = 128; off > 0; off >>= 1) {
        if (t < off) s[t] += s[t + off];
        __syncthreads();
    }
    if (t == 0) bsums[blockIdx.x] = s[0];
}

// single block of 512 threads scans the 391 block sums (exclusive)
__global__ void k_scan512(const int* __restrict__ bsums, int* __restrict__ bscan) {
    __shared__ int s[512];
    int t = threadIdx.x;
    int v = (t < 391) ? bsums[t] : 0;
    s[t] = v;
    __syncthreads();
    for (int off = 1; off < 512; off <<= 1) {
        int x = (t >= off) ? s[t - off] : 0;
        __syncthreads();
        s[t] += x;
        __syncthreads();
    }
    bscan[t] = s[t] - v;  // exclusive
}

__global__ void k_rowptr(const int* __restrict__ deg, const int* __restrict__ bscan,
                         int* __restrict__ rowptr, float* __restrict__ dis) {
    __shared__ int s[256];
    int t = threadIdx.x;
    int i = blockIdx.x * 256 + t;
    int d = (i < NN) ? deg[i] : 0;
    s[t] = d;
    __syncthreads();
    for (int off = 1; off < 256; off <<= 1) {
        int x = (t >= off) ? s[t - off] : 0;
        __syncthreads();
        s[t] += x;
        __syncthreads();
    }
    if (i < NN) {
        int rp = bscan[blockIdx.x] + s[t] - d;  // exclusive global prefix
        rowptr[i] = rp;
        dis[i] = rsqrtf((float)(d + 1));  // +1 self-loop
    }
    if (i == 0) rowptr[NN] = NE;
}

// Atomic-free sharded scatter: pos = rowptr[dst] + blkoff[chunk][dst] + lrank.
// Fire-and-forget stores; shard slice (1.6MB) merges in the (2) XCD L2s that
// write it. blkoff gather is within a 100KB chunk slice -> L2-resident.
__global__ __launch_bounds__(256) void k_build_csr(
    const int4* __restrict__ src4, const int4* __restrict__ dst4,
    const unsigned char* __restrict__ blkoff, const unsigned* __restrict__ lr4,
    const int* __restrict__ rowptr, int* __restrict__ csr) {
    int shard = blockIdx.x & (NSHARD - 1);
    int bsh = blockIdx.x >> 2;
    int stride = (gridDim.x >> 2) * 256;
    int lo = shard * SHARD_W;
    const int NE4 = NE / 4;
    for (int i = bsh * 256 + threadIdx.x; i < NE4; i += stride) {
        int4 d = dst4[i];
        int4 s = src4[i];
        unsigned lr = lr4[i];
        const unsigned char* off = blkoff + (i / CHUNK_I4) * NN;
        unsigned ex = (unsigned)(d.x - lo);
        unsigned ey = (unsigned)(d.y - lo);
        unsigned ez = (unsigned)(d.z - lo);
        unsigned ew = (unsigned)(d.w - lo);
        if (ex < SHARD_W) csr[rowptr[d.x] + off[d.x] + (lr & 255u)] = s.x;
        if (ey < SHARD_W) csr[rowptr[d.y] + off[d.y] + ((lr >> 8) & 255u)] = s.y;
        if (ez < SHARD_W) csr[rowptr[d.z] + off[d.z] + ((lr >> 16) & 255u)] = s.z;
        if (ew < SHARD_W) csr[rowptr[d.w] + off[d.w] + (lr >> 24)] = s.w;
    }
}

// ---------------------------------------------------------------------------
// GEMM layer 1: tsb[row][c] = bf16( (sum_k x[row][k]*W[k][c]) * dis[row] )
// 64 rows x 64 cols per block; thread = 4 rows x 4 cols register tile.
// W and x staged as packed bf16 PAIRS in LDS (one pass, one barrier).
// ---------------------------------------------------------------------------
__global__ __launch_bounds__(256) void k_gemm1(
    const float* __restrict__ x, const float* __restrict__ W,
    const float* __restrict__ dis, unsigned short* __restrict__ tsb) {
    __shared__ unsigned Wsb[128 * 32];
    __shared__ unsigned xsb[64 * 66];
    int t = threadIdx.x;
    int row0 = blockIdx.x * 64;
    for (int i = t; i < 128 * 32; i += 256) {
        int k = i >> 5, c2 = i & 31;
        float2 wv = *(const float2*)&W[k * 64 + 2 * c2];
        Wsb[i] = f2bf(wv.x) | (f2bf(wv.y) << 16);
    }
    for (int i = t; i < 64 * 64; i += 256) {
        int r = i >> 6, k2 = i & 63;
        int gr = row0 + r;
        unsigned p = 0u;
        if (gr < NN) {
            float2 xv = *(const float2*)&x[gr * 128 + 2 * k2];
            p = f2bf(xv.x) | (f2bf(xv.y) << 16);
        }
        xsb[r * 66 + k2] = p;
    }
    __syncthreads();
    int cg = t & 15, rg = t >> 4;
    int col = cg * 4;
    float4 acc0 = {0, 0, 0, 0}, acc1 = {0, 0, 0, 0}, acc2 = {0, 0, 0, 0}, acc3 = {0, 0, 0, 0};
    for (int k2 = 0; k2 < 64; ++k2) {
        uint2 wa = *(const uint2*)&Wsb[(2 * k2) * 32 + cg * 2];
        uint2 wb = *(const uint2*)&Wsb[(2 * k2 + 1) * 32 + cg * 2];
        float wa0 = bflo(wa.x), wa1 = bfhi(wa.x), wa2 = bflo(wa.y), wa3 = bfhi(wa.y);
        float wb0 = bflo(wb.x), wb1 = bfhi(wb.x), wb2 = bflo(wb.y), wb3 = bfhi(wb.y);
        unsigned xp0 = xsb[(rg * 4 + 0) * 66 + k2];
        unsigned xp1 = xsb[(rg * 4 + 1) * 66 + k2];
        unsigned xp2 = xsb[(rg * 4 + 2) * 66 + k2];
        unsigned xp3 = xsb[(rg * 4 + 3) * 66 + k2];
        float xl, xh;
        xl = bflo(xp0); xh = bfhi(xp0);
        acc0.x += xl * wa0 + xh * wb0; acc0.y += xl * wa1 + xh * wb1;
        acc0.z += xl * wa2 + xh * wb2; acc0.w += xl * wa3 + xh * wb3;
        xl = bflo(xp1); xh = bfhi(xp1);
        acc1.x += xl * wa0 + xh * wb0; acc1.y += xl * wa1 + xh * wb1;
        acc1.z += xl * wa2 + xh * wb2; acc1.w += xl * wa3 + xh * wb3;
        xl = bflo(xp2); xh = bfhi(xp2);
        acc2.x += xl * wa0 + xh * wb0; acc2.y += xl * wa1 + xh * wb1;
        acc2.z += xl * wa2 + xh * wb2; acc2.w += xl * wa3 + xh * wb3;
        xl = bflo(xp3); xh = bfhi(xp3);
        acc3.x += xl * wa0 + xh * wb0; acc3.y += xl * wa1 + xh * wb1;
        acc3.z += xl * wa2 + xh * wb2; acc3.w += xl * wa3 + xh * wb3;
    }
    float4 accs[4] = {acc0, acc1, acc2, acc3};
#pragma unroll
    for (int r = 0; r < 4; ++r) {
        int row = row0 + rg * 4 + r;
        if (row < NN) {
            float dv = dis[row];
            float4 a = accs[r];
            uint2 p;
            p.x = f2bf(a.x * dv) | (f2bf(a.y * dv) << 16);
            p.y = f2bf(a.z * dv) | (f2bf(a.w * dv) << 16);
            *(uint2*)&tsb[row * 64 + col] = p;
        }
    }
}

#define FMA4(acc, xv)                                              \
    acc.x += xv.x * w0.x + xv.y * w1.x + xv.z * w2.x + xv.w * w3.x; \
    acc.y += xv.x * w0.y + xv.y * w1.y + xv.z * w2.y + xv.w * w3.y; \
    acc.z += xv.x * w0.z + xv.y * w1.z + xv.z * w2.z + xv.w * w3.z; \
    acc.w += xv.x * w0.w + xv.y * w1.w + xv.z * w2.w + xv.w * w3.w;

// GEMM layer 2: reads bf16 h, writes bf16 ts. K=64.
// K-loop capped at unroll 2: full unroll balloons to 256 VGPR (R13).
__global__ __launch_bounds__(256) void k_gemm2(
    const unsigned short* __restrict__ hb, const float* __restrict__ W,
    const float* __restrict__ dis, unsigned short* __restrict__ tsb) {
    __shared__ float Ws[64 * 64];
    __shared__ float hs[64 * 68];
    int t = threadIdx.x;
    int row0 = blockIdx.x * 64;
    for (int i = t; i < 64 * 64; i += 256) Ws[i] = W[i];
    const unsigned* hb32 = (const unsigned*)hb;  // 2 bf16 per word, row stride 32
    for (int i = t; i < 64 * 32; i += 256) {
        int r = i >> 5, c2 = i & 31;
        int gr = row0 + r;
        unsigned v = (gr < NN) ? hb32[gr * 32 + c2] : 0u;
        hs[r * 68 + 2 * c2] = bflo(v);
        hs[r * 68 + 2 * c2 + 1] = bfhi(v);
    }
    __syncthreads();
    int cg = t & 15, rg = t >> 4;
    int col = cg * 4;
    float4 acc0 = {0, 0, 0, 0}, acc1 = {0, 0, 0, 0}, acc2 = {0, 0, 0, 0}, acc3 = {0, 0, 0, 0};
#pragma unroll 2
    for (int k = 0; k < 64; k += 4) {
        float4 w0 = *(const float4*)&Ws[(k + 0) * 64 + col];
        float4 w1 = *(const float4*)&Ws[(k + 1) * 64 + col];
        float4 w2 = *(const float4*)&Ws[(k + 2) * 64 + col];
        float4 w3 = *(const float4*)&Ws[(k + 3) * 64 + col];
        float4 x0 = *(const float4*)&hs[(rg * 4 + 0) * 68 + k];
        float4 x1 = *(const float4*)&hs[(rg * 4 + 1) * 68 + k];
        float4 x2 = *(const float4*)&hs[(rg * 4 + 2) * 68 + k];
        float4 x3 = *(const float4*)&hs[(rg * 4 + 3) * 68 + k];
        FMA4(acc0, x0) FMA4(acc1, x1) FMA4(acc2, x2) FMA4(acc3, x3)
    }
    float4 accs[4] = {acc0, acc1, acc2, acc3};
#pragma unroll
    for (int r = 0; r < 4; ++r) {
        int row = row0 + rg * 4 + r;
        if (row < NN) {
            float dv = dis[row];
            float4 a = accs[r];
            uint2 p;
            p.x = f2bf(a.x * dv) | (f2bf(a.y * dv) << 16);
            p.y = f2bf(a.z * dv) | (f2bf(a.w * dv) << 16);
            *(uint2*)&tsb[row * 64 + col] = p;
        }
    }
}

// ---------------------------------------------------------------------------
// Fused aggregation + dis scale + bias + ReLU, bf16 rows (128 B each).
// One 64-lane wave per node; EIGHTH-wave (8 lanes x 16B uint4) per edge ->
// 8 edges per load instruction, 16 in flight with unroll 2. lane = feature
// OCTET (uint4 = 8 bf16). f32 accum; octets combined via shfl_xor(8/16/32).
// ---------------------------------------------------------------------------
__global__ __launch_bounds__(256) void k_agg_relu(
    const unsigned short* __restrict__ tsb, const int* __restrict__ rowptr,
    const int* __restrict__ csr, const float* __restrict__ dis,
    const float* __restrict__ b, unsigned short* __restrict__ hb) {
    int node = blockIdx.x * 4 + (threadIdx.x >> 6);
    if (node >= NN) return;
    int lane = threadIdx.x & 63;
    int oct = lane >> 3;  // octet 0..7
    int fl = lane & 7;    // feature octet: features 8*fl .. 8*fl+7
    const uint4* ts128 = (const uint4*)tsb;  // row stride 8 uint4
    float a0 = 0.f, a1 = 0.f, a2 = 0.f, a3 = 0.f, a4 = 0.f, a5 = 0.f, a6 = 0.f, a7 = 0.f;
    if (oct == 0) {  // self-loop term, added once
        uint4 v = ts128[node * 8 + fl];
        a0 += bflo(v.x); a1 += bfhi(v.x); a2 += bflo(v.y); a3 += bfhi(v.y);
        a4 += bflo(v.z); a5 += bfhi(v.z); a6 += bflo(v.w); a7 += bfhi(v.w);
    }
    int e = rowptr[node] + oct, end = rowptr[node + 1];
    // per-octet stride 8; unroll 2 -> 16 edges in flight per wave
    for (; e + 8 < end; e += 16) {
        int s0 = csr[e];
        int s1 = csr[e + 8];
        uint4 v0 = ts128[s0 * 8 + fl];
        uint4 v1 = ts128[s1 * 8 + fl];
        a0 += bflo(v0.x) + bflo(v1.x); a1 += bfhi(v0.x) + bfhi(v1.x);
        a2 += bflo(v0.y) + bflo(v1.y); a3 += bfhi(v0.y) + bfhi(v1.y);
        a4 += bflo(v0.z) + bflo(v1.z); a5 += bfhi(v0.z) + bfhi(v1.z);
        a6 += bflo(v0.w) + bflo(v1.w); a7 += bfhi(v0.w) + bfhi(v1.w);
    }
    if (e < end) {
        uint4 v = ts128[csr[e] * 8 + fl];
        a0 += bflo(v.x); a1 += bfhi(v.x); a2 += bflo(v.y); a3 += bfhi(v.y);
        a4 += bflo(v.z); a5 += bfhi(v.z); a6 += bflo(v.w); a7 += bfhi(v.w);
    }
#pragma unroll
    for (int off = 8; off <= 32; off <<= 1) {
        a0 += __shfl_xor(a0, off); a1 += __shfl_xor(a1, off);
        a2 += __shfl_xor(a2, off); a3 += __shfl_xor(a3, off);
        a4 += __shfl_xor(a4, off); a5 += __shfl_xor(a5, off);
        a6 += __shfl_xor(a6, off); a7 += __shfl_xor(a7, off);
    }
    if (oct == 0) {
        float dv = dis[node];
        float v0 = fmaxf(a0 * dv + b[8 * fl + 0], 0.f);
        float v1 = fmaxf(a1 * dv + b[8 * fl + 1], 0.f);
        float v2 = fmaxf(a2 * dv + b[8 * fl + 2], 0.f);
        float v3 = fmaxf(a3 * dv + b[8 * fl + 3], 0.f);
        float v4 = fmaxf(a4 * dv + b[8 * fl + 4], 0.f);
        float v5 = fmaxf(a5 * dv + b[8 * fl + 5], 0.f);
        float v6 = fmaxf(a6 * dv + b[8 * fl + 6], 0.f);
        float v7 = fmaxf(a7 * dv + b[8 * fl + 7], 0.f);
        uint4 p;
        p.x = f2bf(v0) | (f2bf(v1) << 16);
        p.y = f2bf(v2) | (f2bf(v3) << 16);
        p.z = f2bf(v4) | (f2bf(v5) << 16);
        p.w = f2bf(v6) | (f2bf(v7) << 16);
        ((uint4*)hb)[node * 8 + fl] = p;
    }
}

// ---------------------------------------------------------------------------
// Layer 3 projection: t3[row] = dot(h_bf16[row], W3) * dis[row]   (f32 out)
// ---------------------------------------------------------------------------
__global__ void k_gemm3(const unsigned short* __restrict__ hb, const float* __restrict__ W3,
                        const float* __restrict__ dis, float* __restrict__ t3) {
    __shared__ float Ws[64];
    if (threadIdx.x < 64) Ws[threadIdx.x] = W3[threadIdx.x];
    __syncthreads();
    int row = blockIdx.x * 256 + threadIdx.x;
    if (row >= NN) return;
    const uint4* hp = (const uint4*)(hb + row * 64);  // 8 x uint4 = 128 B
    float acc = 0.f;
#pragma unroll
    for (int k = 0; k < 8; ++k) {
        uint4 v = hp[k];
        acc += bflo(v.x) * Ws[8 * k + 0] + bfhi(v.x) * Ws[8 * k + 1]
             + bflo(v.y) * Ws[8 * k + 2] + bfhi(v.y) * Ws[8 * k + 3]
             + bflo(v.z) * Ws[8 * k + 4] + bfhi(v.z) * Ws[8 * k + 5]
             + bflo(v.w) * Ws[8 * k + 6] + bfhi(v.w) * Ws[8 * k + 7];
    }
    t3[row] = acc * dis[row];
}

// Fused layer-3 aggregation + sigmoid. One thread per node; unroll 4.
__global__ void k_out(const float* __restrict__ t3, const int* __restrict__ rowptr,
                      const int* __restrict__ csr, const float* __restrict__ dis,
                      const float* __restrict__ b3, float* __restrict__ out) {
    int i = blockIdx.x * 256 + threadIdx.x;
    if (i >= NN) return;
    float acc = t3[i];
    float acc1 = 0.f, acc2 = 0.f, acc3 = 0.f;
    int e = rowptr[i], end = rowptr[i + 1];
    for (; e + 4 <= end; e += 4) {
        acc += t3[csr[e]];
        acc1 += t3[csr[e + 1]];
        acc2 += t3[csr[e + 2]];
        acc3 += t3[csr[e + 3]];
    }
    for (; e < end; ++e) acc += t3[csr[e]];
    float z = ((acc + acc1) + (acc2 + acc3)) * dis[i] + b3[0];
    out[i] = 1.f / (1.f + __expf(-z));
}

// ---------------------------------------------------------------------------
extern "C" void kernel_launch(void* const* d_in, const int* in_sizes, int n_in,
                              void* d_out, int out_size, void* d_ws, size_t ws_size,
                              hipStream_t stream) {
    const float* x  = (const float*)d_in[0];   // N x 128
    const float* W1 = (const float*)d_in[1];   // 128 x 64
    const float* b1 = (const float*)d_in[2];   // 64
    const float* W2 = (const float*)d_in[3];   // 64 x 64
    const float* b2 = (const float*)d_in[4];   // 64
    const float* W3 = (const float*)d_in[5];   // 64 x 1
    const float* b3 = (const float*)d_in[6];   // 1
    const int*   ei = (const int*)d_in[7];     // 2 x E
    const int* src = ei;
    const int* dst = ei + NE;
    float* out = (float*)d_out;

    // Workspace layout
    unsigned short* TSB = (unsigned short*)d_ws;          // N*64 bf16 (ts)
    unsigned short* HB  = TSB + (size_t)NN * 64;          // N*64 bf16 (h)
    float* dis    = (float*)(HB + (size_t)NN * 64);       // N
    float* t3     = dis + NN;                             // N
    int*   deg    = (int*)(t3 + NN);                      // N
    int*   rowptr = deg + NN;                             // N+1 (+pad)
    int*   bsums  = rowptr + NN + 8;                      // 512
    int*   bscan  = bsums + 512;                          // 512
    int*   csr    = bscan + 512;                          // E
    // Aliased scratch (dead before the aliasee is first written):
    unsigned char* lrank = (unsigned char*)TSB;  // E bytes; dead before k_gemm1
    unsigned char* cnt   = (unsigned char*)HB;   // NCHUNK*NN bytes; dead before k_agg_relu

    const int nbN = (NN + 255) / 256;       // 391
    const int nbG = (NN + 63) / 64;         // 1563
    const int nbA = (NN + 3) / 4;           // 25000

    // CSR build + normalization (LDS counting sort, no device-scope atomics)
    k_cnt<<<NSHARD * NCHUNK, 256, 0, stream>>>((const int4*)dst, cnt, lrank);
    k_blkscan<<<(NN / 4 + 255) / 256, 256, 0, stream>>>((unsigned*)cnt, (int4*)deg);
    k_bsum<<<nbN, 256, 0, stream>>>(deg, bsums);
    k_scan512<<<1, 512, 0, stream>>>(bsums, bscan);
    k_rowptr<<<nbN, 256, 0, stream>>>(deg, bscan, rowptr, dis);
    k_build_csr<<<2048, 256, 0, stream>>>((const int4*)src, (const int4*)dst,
                                          cnt, (const unsigned*)lrank, rowptr, csr);

    // Layer 1
    k_gemm1<<<nbG, 256, 0, stream>>>(x, W1, dis, TSB);
    k_agg_relu<<<nbA, 256, 0, stream>>>(TSB, rowptr, csr, dis, b1, HB);

    // Layer 2
    k_gemm2<<<nbG, 256, 0, stream>>>(HB, W2, dis, TSB);
    k_agg_relu<<<nbA, 256, 0, stream>>>(TSB, rowptr, csr, dis, b2, HB);

    // Layer 3
    k_gemm3<<<nbN, 256, 0, stream>>>(HB, W3, dis, t3);
    k_out<<<nbN, 256, 0, stream>>>(t3, rowptr, csr, dis, b3, out);
}

// Round 2
// 297.118 us; speedup vs baseline: 1.2945x; 1.1438x over previous
//
#include <hip/hip_runtime.h>
#include <math.h>

// N=100000 nodes, E=1600000 edges, features 128 -> 64 -> 64 -> 1.
// R23 = R22 with k_gemm1/k_gemm2 moved to MFMA (mfma_f32_16x16x32_bf16).
// R22 rocprof: k_gemm1 was 65us with MfmaUtil=0, VALUBusy=50%, hbm 7.4% ->
// VALU-bound on scalar bf16 emulation (unpack shifts + FMAs on vector ALU).
// Useful FLOPs (1.64G) are ~0.7us at MFMA rate -> kernels become staging-
// bound (~13-18us). Both layers already use bf16-rounded operands, so MFMA
// bf16 (f32 accum) is the same numeric class; W2 is split hi+lo bf16
// (2x MFMA) to preserve layer-2's f32-weight precision.
// Fragment notes: A row m = lane&15, B col n = lane&15, k-group = lane>>4,
// 8 consecutive k per lane (ds_read_b128 from row-major A / transposed W);
// C/D: col = lane&15, row = (lane>>4)*4 + reg (HW-verified mapping).
// LDS tiles padded +8 bf16/row -> row stride = 4 mod 32 words -> 2-way bank
// aliasing (free). CSR build: R22's LDS counting sort (no global atomics).
// NOTE: __launch_bounds__(256,4) is 0-for-4 on this harness — do not use.
#define NN 100000
#define NE 1600000
#define NSHARD 4
#define SHARD_W (NN / NSHARD)   // 25000 exactly
#define NCHUNK 64
#define CHUNK_E (NE / NCHUNK)   // 25000 edges per chunk
#define CHUNK_I4 (CHUNK_E / 4)  // 6250 int4 per chunk

typedef __attribute__((ext_vector_type(8))) short bf16x8;
typedef __attribute__((ext_vector_type(4))) float f32x4;

// bf16 helpers (manual, round-to-nearest-even; intermediates only)
__device__ inline unsigned f2bf(float f) {
    unsigned u = __float_as_uint(f);
    u += 0x7FFFu + ((u >> 16) & 1u);
    return u >> 16;
}
__device__ inline float bflo(unsigned v) { return __uint_as_float(v << 16); }
__device__ inline float bfhi(unsigned v) { return __uint_as_float(v & 0xFFFF0000u); }

// ---------------------------------------------------------------------------
// CSR build: LDS counting-sort (no device-scope atomics).
// ---------------------------------------------------------------------------
__global__ __launch_bounds__(256) void k_cnt(const int4* __restrict__ dst4,
                                             unsigned char* __restrict__ cnt,
                                             unsigned char* __restrict__ lrank) {
    __shared__ __align__(16) unsigned ldeg[SHARD_W];  // 100 KB (gfx950: 160 KB/CU)
    int t = threadIdx.x;
    int shard = blockIdx.x & (NSHARD - 1);
    int b = blockIdx.x >> 2;
    int lo = shard * SHARD_W;
    for (int i = t; i < SHARD_W; i += 256) ldeg[i] = 0u;
    __syncthreads();
    const int4* p = dst4 + b * CHUNK_I4;
    unsigned char* lr = lrank + b * CHUNK_E;
#pragma unroll 4
    for (int j = t; j < CHUNK_I4; j += 256) {
        int4 d = p[j];
        unsigned ex = (unsigned)(d.x - lo);
        unsigned ey = (unsigned)(d.y - lo);
        unsigned ez = (unsigned)(d.z - lo);
        unsigned ew = (unsigned)(d.w - lo);
        if (ex < SHARD_W) lr[4 * j + 0] = (unsigned char)atomicAdd(&ldeg[ex], 1u);
        if (ey < SHARD_W) lr[4 * j + 1] = (unsigned char)atomicAdd(&ldeg[ey], 1u);
        if (ez < SHARD_W) lr[4 * j + 2] = (unsigned char)atomicAdd(&ldeg[ez], 1u);
        if (ew < SHARD_W) lr[4 * j + 3] = (unsigned char)atomicAdd(&ldeg[ew], 1u);
    }
    __syncthreads();
    unsigned* cb32 = (unsigned*)cnt + b * (NN / 4) + shard * (SHARD_W / 4);
    for (int i = t; i < SHARD_W / 4; i += 256) {
        uint4 v = *(const uint4*)&ldeg[4 * i];
        cb32[i] = (v.x & 255u) | ((v.y & 255u) << 8) | ((v.z & 255u) << 16)
                | ((v.w & 255u) << 24);
    }
}

// Pass B: per node, exclusive prefix across the 64 chunk counts (in place,
// byte-packed, 4 nodes/thread); row total -> deg.
__global__ __launch_bounds__(256) void k_blkscan(unsigned* __restrict__ cnt32,
                                                 int4* __restrict__ deg4) {
    int i = blockIdx.x * 256 + threadIdx.x;
    if (i >= NN / 4) return;
    unsigned c[NCHUNK];
#pragma unroll
    for (int b = 0; b < NCHUNK; ++b) c[b] = cnt32[b * (NN / 4) + i];
    unsigned a0 = 0, a1 = 0, a2 = 0, a3 = 0;
#pragma unroll
    for (int b = 0; b < NCHUNK; ++b) {
        unsigned v = c[b];
        cnt32[b * (NN / 4) + i] = a0 | (a1 << 8) | (a2 << 16) | (a3 << 24);
        a0 += v & 255u;
        a1 += (v >> 8) & 255u;
        a2 += (v >> 16) & 255u;
        a3 += v >> 24;
    }
    deg4[i] = make_int4((int)a0, (int)a1, (int)a2, (int)a3);
}

__global__ void k_bsum(const int* __restrict__ deg, int* __restrict__ bsums) {
    __shared__ int s[256];
    int t = threadIdx.x;
    int i = blockIdx.x * 256 + t;
    s[t] = (i < NN) ? deg[i] : 0;
    __syncthreads();
    for (int off = 128; off > 0; off >>= 1) {
        if (t < off) s[t] += s[t + off];
        __syncthreads();
    }
    if (t == 0) bsums[blockIdx.x] = s[0];
}

// single block of 512 threads scans the 391 block sums (exclusive)
__global__ void k_scan512(const int* __restrict__ bsums, int* __restrict__ bscan) {
    __shared__ int s[512];
    int t = threadIdx.x;
    int v = (t < 391) ? bsums[t] : 0;
    s[t] = v;
    __syncthreads();
    for (int off = 1; off < 512; off <<= 1) {
        int x = (t >= off) ? s[t - off] : 0;
        __syncthreads();
        s[t] += x;
        __syncthreads();
    }
    bscan[t] = s[t] - v;  // exclusive
}

__global__ void k_rowptr(const int* __restrict__ deg, const int* __restrict__ bscan,
                         int* __restrict__ rowptr, float* __restrict__ dis) {
    __shared__ int s[256];
    int t = threadIdx.x;
    int i = blockIdx.x * 256 + t;
    int d = (i < NN) ? deg[i] : 0;
    s[t] = d;
    __syncthreads();
    for (int off = 1; off < 256; off <<= 1) {
        int x = (t >= off) ? s[t - off] : 0;
        __syncthreads();
        s[t] += x;
        __syncthreads();
    }
    if (i < NN) {
        int rp = bscan[blockIdx.x] + s[t] - d;  // exclusive global prefix
        rowptr[i] = rp;
        dis[i] = rsqrtf((float)(d + 1));  // +1 self-loop
    }
    if (i == 0) rowptr[NN] = NE;
}

// Atomic-free sharded scatter: pos = rowptr[dst] + blkoff[chunk][dst] + lrank.
__global__ __launch_bounds__(256) void k_build_csr(
    const int4* __restrict__ src4, const int4* __restrict__ dst4,
    const unsigned char* __restrict__ blkoff, const unsigned* __restrict__ lr4,
    const int* __restrict__ rowptr, int* __restrict__ csr) {
    int shard = blockIdx.x & (NSHARD - 1);
    int bsh = blockIdx.x >> 2;
    int stride = (gridDim.x >> 2) * 256;
    int lo = shard * SHARD_W;
    const int NE4 = NE / 4;
    for (int i = bsh * 256 + threadIdx.x; i < NE4; i += stride) {
        int4 d = dst4[i];
        int4 s = src4[i];
        unsigned lr = lr4[i];
        const unsigned char* off = blkoff + (i / CHUNK_I4) * NN;
        unsigned ex = (unsigned)(d.x - lo);
        unsigned ey = (unsigned)(d.y - lo);
        unsigned ez = (unsigned)(d.z - lo);
        unsigned ew = (unsigned)(d.w - lo);
        if (ex < SHARD_W) csr[rowptr[d.x] + off[d.x] + (lr & 255u)] = s.x;
        if (ey < SHARD_W) csr[rowptr[d.y] + off[d.y] + ((lr >> 8) & 255u)] = s.y;
        if (ez < SHARD_W) csr[rowptr[d.z] + off[d.z] + ((lr >> 16) & 255u)] = s.z;
        if (ew < SHARD_W) csr[rowptr[d.w] + off[d.w] + (lr >> 24)] = s.w;
    }
}

// ---------------------------------------------------------------------------
// GEMM layer 1 (MFMA): tsb[row][c] = bf16( (x[row]@W1)[c] * dis[row] )
// Block = 64 rows; wave w = rows 16w..16w+15 x all 64 cols.
// x, W^T staged as bf16 in LDS (pad +8 -> 2-way bank aliasing, free).
// Per wave: 4 k-blocks x 4 col-tiles = 16 MFMAs.
// ---------------------------------------------------------------------------
#define XS_LD 136  // 128 + 8 pad (bf16 units); stride%32words==4
__global__ __launch_bounds__(256) void k_gemm1(
    const float* __restrict__ x, const float* __restrict__ W,
    const float* __restrict__ dis, unsigned short* __restrict__ tsb) {
    __shared__ unsigned short xs[64 * XS_LD];
    __shared__ unsigned short wt[64 * XS_LD];
    int t = threadIdx.x;
    int row0 = blockIdx.x * 64;
    // stage W^T as bf16: wt[n][k]  (reads coalesced over n)
    for (int i = t; i < 64 * 64; i += 256) {
        int n = i & 63, k2 = i >> 6;
        float w0 = W[(2 * k2) * 64 + n];
        float w1 = W[(2 * k2 + 1) * 64 + n];
        *(unsigned*)&wt[n * XS_LD + 2 * k2] = f2bf(w0) | (f2bf(w1) << 16);
    }
    // stage x rows as bf16: xs[r][k]  (float4 loads, coalesced)
    for (int i = t; i < 64 * 32; i += 256) {
        int r = i >> 5, c4 = i & 31;
        int gr = row0 + r;
        uint2 p = {0u, 0u};
        if (gr < NN) {
            float4 v = *(const float4*)&x[gr * 128 + 4 * c4];
            p.x = f2bf(v.x) | (f2bf(v.y) << 16);
            p.y = f2bf(v.z) | (f2bf(v.w) << 16);
        }
        *(uint2*)&xs[r * XS_LD + 4 * c4] = p;
    }
    __syncthreads();
    int w = t >> 6, l = t & 63;
    int lm = l & 15, lg = l >> 4;
    const unsigned short* ap = &xs[(16 * w + lm) * XS_LD + 8 * lg];
    const unsigned short* bp = &wt[lm * XS_LD + 8 * lg];
    f32x4 acc0 = {0, 0, 0, 0}, acc1 = {0, 0, 0, 0}, acc2 = {0, 0, 0, 0}, acc3 = {0, 0, 0, 0};
#pragma unroll
    for (int kb = 0; kb < 4; ++kb) {
        bf16x8 a  = *(const bf16x8*)(ap + 32 * kb);
        bf16x8 b0 = *(const bf16x8*)(bp + 32 * kb);
        bf16x8 b1 = *(const bf16x8*)(bp + 16 * XS_LD + 32 * kb);
        bf16x8 b2 = *(const bf16x8*)(bp + 32 * XS_LD + 32 * kb);
        bf16x8 b3 = *(const bf16x8*)(bp + 48 * XS_LD + 32 * kb);
        acc0 = __builtin_amdgcn_mfma_f32_16x16x32_bf16(a, b0, acc0, 0, 0, 0);
        acc1 = __builtin_amdgcn_mfma_f32_16x16x32_bf16(a, b1, acc1, 0, 0, 0);
        acc2 = __builtin_amdgcn_mfma_f32_16x16x32_bf16(a, b2, acc2, 0, 0, 0);
        acc3 = __builtin_amdgcn_mfma_f32_16x16x32_bf16(a, b3, acc3, 0, 0, 0);
    }
    int rbase = row0 + 16 * w + 4 * lg;
#pragma unroll
    for (int r = 0; r < 4; ++r) {
        int row = rbase + r;
        if (row < NN) {
            float dv = dis[row];
            unsigned short* o = &tsb[row * 64 + lm];
            o[0]  = (unsigned short)f2bf(acc0[r] * dv);
            o[16] = (unsigned short)f2bf(acc1[r] * dv);
            o[32] = (unsigned short)f2bf(acc2[r] * dv);
            o[48] = (unsigned short)f2bf(acc3[r] * dv);
        }
    }
}

// ---------------------------------------------------------------------------
// GEMM layer 2 (MFMA): K=64, h is bf16 already. W2 split into bf16 hi+lo
// (residual) -> 2x MFMAs, keeps layer-2 precision at f32-weight level.
// ---------------------------------------------------------------------------
#define HS_LD 72  // 64 + 8 pad (bf16 units); stride%32words==4
__global__ __launch_bounds__(256) void k_gemm2(
    const unsigned short* __restrict__ hb, const float* __restrict__ W,
    const float* __restrict__ dis, unsigned short* __restrict__ tsb) {
    __shared__ unsigned short hs[64 * HS_LD];
    __shared__ unsigned short wh[64 * HS_LD];
    __shared__ unsigned short wl[64 * HS_LD];
    int t = threadIdx.x;
    int row0 = blockIdx.x * 64;
    // stage W^T split: wh[n][k] = bf16(W), wl[n][k] = bf16(W - wh)
    for (int i = t; i < 64 * 32; i += 256) {
        int n = i & 63, k2 = i >> 6;
        float w0 = W[(2 * k2) * 64 + n];
        float w1 = W[(2 * k2 + 1) * 64 + n];
        unsigned h0 = f2bf(w0), h1 = f2bf(w1);
        *(unsigned*)&wh[n * HS_LD + 2 * k2] = h0 | (h1 << 16);
        float r0 = w0 - bflo(h0), r1 = w1 - bflo(h1);
        *(unsigned*)&wl[n * HS_LD + 2 * k2] = f2bf(r0) | (f2bf(r1) << 16);
    }
    // stage h rows (bf16 passthrough, uint4 = 8 bf16)
    const uint4* h4 = (const uint4*)hb;
    for (int i = t; i < 64 * 8; i += 256) {
        int r = i >> 3, c8 = i & 7;
        int gr = row0 + r;
        uint4 v = (gr < NN) ? h4[gr * 8 + c8] : make_uint4(0u, 0u, 0u, 0u);
        *(uint4*)&hs[r * HS_LD + 8 * c8] = v;
    }
    __syncthreads();
    int w = t >> 6, l = t & 63;
    int lm = l & 15, lg = l >> 4;
    const unsigned short* ap = &hs[(16 * w + lm) * HS_LD + 8 * lg];
    const unsigned short* bh = &wh[lm * HS_LD + 8 * lg];
    const unsigned short* bl = &wl[lm * HS_LD + 8 * lg];
    f32x4 acc0 = {0, 0, 0, 0}, acc1 = {0, 0, 0, 0}, acc2 = {0, 0, 0, 0}, acc3 = {0, 0, 0, 0};
#pragma unroll
    for (int kb = 0; kb < 2; ++kb) {
        bf16x8 a  = *(const bf16x8*)(ap + 32 * kb);
        bf16x8 h0 = *(const bf16x8*)(bh + 32 * kb);
        bf16x8 h1 = *(const bf16x8*)(bh + 16 * HS_LD + 32 * kb);
        bf16x8 h2 = *(const bf16x8*)(bh + 32 * HS_LD + 32 * kb);
        bf16x8 h3 = *(const bf16x8*)(bh + 48 * HS_LD + 32 * kb);
        bf16x8 l0 = *(const bf16x8*)(bl + 32 * kb);
        bf16x8 l1 = *(const bf16x8*)(bl + 16 * HS_LD + 32 * kb);
        bf16x8 l2 = *(const bf16x8*)(bl + 32 * HS_LD + 32 * kb);
        bf16x8 l3 = *(const bf16x8*)(bl + 48 * HS_LD + 32 * kb);
        acc0 = __builtin_amdgcn_mfma_f32_16x16x32_bf16(a, h0, acc0, 0, 0, 0);
        acc1 = __builtin_amdgcn_mfma_f32_16x16x32_bf16(a, h1, acc1, 0, 0, 0);
        acc2 = __builtin_amdgcn_mfma_f32_16x16x32_bf16(a, h2, acc2, 0, 0, 0);
        acc3 = __builtin_amdgcn_mfma_f32_16x16x32_bf16(a, h3, acc3, 0, 0, 0);
        acc0 = __builtin_amdgcn_mfma_f32_16x16x32_bf16(a, l0, acc0, 0, 0, 0);
        acc1 = __builtin_amdgcn_mfma_f32_16x16x32_bf16(a, l1, acc1, 0, 0, 0);
        acc2 = __builtin_amdgcn_mfma_f32_16x16x32_bf16(a, l2, acc2, 0, 0, 0);
        acc3 = __builtin_amdgcn_mfma_f32_16x16x32_bf16(a, l3, acc3, 0, 0, 0);
    }
    int rbase = row0 + 16 * w + 4 * lg;
#pragma unroll
    for (int r = 0; r < 4; ++r) {
        int row = rbase + r;
        if (row < NN) {
            float dv = dis[row];
            unsigned short* o = &tsb[row * 64 + lm];
            o[0]  = (unsigned short)f2bf(acc0[r] * dv);
            o[16] = (unsigned short)f2bf(acc1[r] * dv);
            o[32] = (unsigned short)f2bf(acc2[r] * dv);
            o[48] = (unsigned short)f2bf(acc3[r] * dv);
        }
    }
}

// ---------------------------------------------------------------------------
// Fused aggregation + dis scale + bias + ReLU, bf16 rows (128 B each).
// One 64-lane wave per node; EIGHTH-wave (8 lanes x 16B uint4) per edge ->
// 8 edges per load instruction, 16 in flight with unroll 2.
// ---------------------------------------------------------------------------
__global__ __launch_bounds__(256) void k_agg_relu(
    const unsigned short* __restrict__ tsb, const int* __restrict__ rowptr,
    const int* __restrict__ csr, const float* __restrict__ dis,
    const float* __restrict__ b, unsigned short* __restrict__ hb) {
    int node = blockIdx.x * 4 + (threadIdx.x >> 6);
    if (node >= NN) return;
    int lane = threadIdx.x & 63;
    int oct = lane >> 3;  // octet 0..7
    int fl = lane & 7;    // feature octet: features 8*fl .. 8*fl+7
    const uint4* ts128 = (const uint4*)tsb;  // row stride 8 uint4
    float a0 = 0.f, a1 = 0.f, a2 = 0.f, a3 = 0.f, a4 = 0.f, a5 = 0.f, a6 = 0.f, a7 = 0.f;
    if (oct == 0) {  // self-loop term, added once
        uint4 v = ts128[node * 8 + fl];
        a0 += bflo(v.x); a1 += bfhi(v.x); a2 += bflo(v.y); a3 += bfhi(v.y);
        a4 += bflo(v.z); a5 += bfhi(v.z); a6 += bflo(v.w); a7 += bfhi(v.w);
    }
    int e = rowptr[node] + oct, end = rowptr[node + 1];
    for (; e + 8 < end; e += 16) {
        int s0 = csr[e];
        int s1 = csr[e + 8];
        uint4 v0 = ts128[s0 * 8 + fl];
        uint4 v1 = ts128[s1 * 8 + fl];
        a0 += bflo(v0.x) + bflo(v1.x); a1 += bfhi(v0.x) + bfhi(v1.x);
        a2 += bflo(v0.y) + bflo(v1.y); a3 += bfhi(v0.y) + bfhi(v1.y);
        a4 += bflo(v0.z) + bflo(v1.z); a5 += bfhi(v0.z) + bfhi(v1.z);
        a6 += bflo(v0.w) + bflo(v1.w); a7 += bfhi(v0.w) + bfhi(v1.w);
    }
    if (e < end) {
        uint4 v = ts128[csr[e] * 8 + fl];
        a0 += bflo(v.x); a1 += bfhi(v.x); a2 += bflo(v.y); a3 += bfhi(v.y);
        a4 += bflo(v.z); a5 += bfhi(v.z); a6 += bflo(v.w); a7 += bfhi(v.w);
    }
#pragma unroll
    for (int off = 8; off <= 32; off <<= 1) {
        a0 += __shfl_xor(a0, off); a1 += __shfl_xor(a1, off);
        a2 += __shfl_xor(a2, off); a3 += __shfl_xor(a3, off);
        a4 += __shfl_xor(a4, off); a5 += __shfl_xor(a5, off);
        a6 += __shfl_xor(a6, off); a7 += __shfl_xor(a7, off);
    }
    if (oct == 0) {
        float dv = dis[node];
        float v0 = fmaxf(a0 * dv + b[8 * fl + 0], 0.f);
        float v1 = fmaxf(a1 * dv + b[8 * fl + 1], 0.f);
        float v2 = fmaxf(a2 * dv + b[8 * fl + 2], 0.f);
        float v3 = fmaxf(a3 * dv + b[8 * fl + 3], 0.f);
        float v4 = fmaxf(a4 * dv + b[8 * fl + 4], 0.f);
        float v5 = fmaxf(a5 * dv + b[8 * fl + 5], 0.f);
        float v6 = fmaxf(a6 * dv + b[8 * fl + 6], 0.f);
        float v7 = fmaxf(a7 * dv + b[8 * fl + 7], 0.f);
        uint4 p;
        p.x = f2bf(v0) | (f2bf(v1) << 16);
        p.y = f2bf(v2) | (f2bf(v3) << 16);
        p.z = f2bf(v4) | (f2bf(v5) << 16);
        p.w = f2bf(v6) | (f2bf(v7) << 16);
        ((uint4*)hb)[node * 8 + fl] = p;
    }
}

// ---------------------------------------------------------------------------
// Layer 3 projection: t3[row] = dot(h_bf16[row], W3) * dis[row]   (f32 out)
// ---------------------------------------------------------------------------
__global__ void k_gemm3(const unsigned short* __restrict__ hb, const float* __restrict__ W3,
                        const float* __restrict__ dis, float* __restrict__ t3) {
    __shared__ float Ws[64];
    if (threadIdx.x < 64) Ws[threadIdx.x] = W3[threadIdx.x];
    __syncthreads();
    int row = blockIdx.x * 256 + threadIdx.x;
    if (row >= NN) return;
    const uint4* hp = (const uint4*)(hb + row * 64);  // 8 x uint4 = 128 B
    float acc = 0.f;
#pragma unroll
    for (int k = 0; k < 8; ++k) {
        uint4 v = hp[k];
        acc += bflo(v.x) * Ws[8 * k + 0] + bfhi(v.x) * Ws[8 * k + 1]
             + bflo(v.y) * Ws[8 * k + 2] + bfhi(v.y) * Ws[8 * k + 3]
             + bflo(v.z) * Ws[8 * k + 4] + bfhi(v.z) * Ws[8 * k + 5]
             + bflo(v.w) * Ws[8 * k + 6] + bfhi(v.w) * Ws[8 * k + 7];
    }
    t3[row] = acc * dis[row];
}

// Fused layer-3 aggregation + sigmoid. One thread per node; unroll 4.
__global__ void k_out(const float* __restrict__ t3, const int* __restrict__ rowptr,
                      const int* __restrict__ csr, const float* __restrict__ dis,
                      const float* __restrict__ b3, float* __restrict__ out) {
    int i = blockIdx.x * 256 + threadIdx.x;
    if (i >= NN) return;
    float acc = t3[i];
    float acc1 = 0.f, acc2 = 0.f, acc3 = 0.f;
    int e = rowptr[i], end = rowptr[i + 1];
    for (; e + 4 <= end; e += 4) {
        acc += t3[csr[e]];
        acc1 += t3[csr[e + 1]];
        acc2 += t3[csr[e + 2]];
        acc3 += t3[csr[e + 3]];
    }
    for (; e < end; ++e) acc += t3[csr[e]];
    float z = ((acc + acc1) + (acc2 + acc3)) * dis[i] + b3[0];
    out[i] = 1.f / (1.f + __expf(-z));
}

// ---------------------------------------------------------------------------
extern "C" void kernel_launch(void* const* d_in, const int* in_sizes, int n_in,
                              void* d_out, int out_size, void* d_ws, size_t ws_size,
                              hipStream_t stream) {
    const float* x  = (const float*)d_in[0];   // N x 128
    const float* W1 = (const float*)d_in[1];   // 128 x 64
    const float* b1 = (const float*)d_in[2];   // 64
    const float* W2 = (const float*)d_in[3];   // 64 x 64
    const float* b2 = (const float*)d_in[4];   // 64
    const float* W3 = (const float*)d_in[5];   // 64 x 1
    const float* b3 = (const float*)d_in[6];   // 1
    const int*   ei = (const int*)d_in[7];     // 2 x E
    const int* src = ei;
    const int* dst = ei + NE;
    float* out = (float*)d_out;

    // Workspace layout
    unsigned short* TSB = (unsigned short*)d_ws;          // N*64 bf16 (ts)
    unsigned short* HB  = TSB + (size_t)NN * 64;          // N*64 bf16 (h)
    float* dis    = (float*)(HB + (size_t)NN * 64);       // N
    float* t3     = dis + NN;                             // N
    int*   deg    = (int*)(t3 + NN);                      // N
    int*   rowptr = deg + NN;                             // N+1 (+pad)
    int*   bsums  = rowptr + NN + 8;                      // 512
    int*   bscan  = bsums + 512;                          // 512
    int*   csr    = bscan + 512;                          // E
    // Aliased scratch (dead before the aliasee is first written):
    unsigned char* lrank = (unsigned char*)TSB;  // E bytes; dead before k_gemm1
    unsigned char* cnt   = (unsigned char*)HB;   // NCHUNK*NN bytes; dead before k_agg_relu

    const int nbN = (NN + 255) / 256;       // 391
    const int nbG = (NN + 63) / 64;         // 1563
    const int nbA = (NN + 3) / 4;           // 25000

    // CSR build + normalization (LDS counting sort, no device-scope atomics)
    k_cnt<<<NSHARD * NCHUNK, 256, 0, stream>>>((const int4*)dst, cnt, lrank);
    k_blkscan<<<(NN / 4 + 255) / 256, 256, 0, stream>>>((unsigned*)cnt, (int4*)deg);
    k_bsum<<<nbN, 256, 0, stream>>>(deg, bsums);
    k_scan512<<<1, 512, 0, stream>>>(bsums, bscan);
    k_rowptr<<<nbN, 256, 0, stream>>>(deg, bscan, rowptr, dis);
    k_build_csr<<<2048, 256, 0, stream>>>((const int4*)src, (const int4*)dst,
                                          cnt, (const unsigned*)lrank, rowptr, csr);

    // Layer 1
    k_gemm1<<<nbG, 256, 0, stream>>>(x, W1, dis, TSB);
    k_agg_relu<<<nbA, 256, 0, stream>>>(TSB, rowptr, csr, dis, b1, HB);

    // Layer 2
    k_gemm2<<<nbG, 256, 0, stream>>>(HB, W2, dis, TSB);
    k_agg_relu<<<nbA, 256, 0, stream>>>(TSB, rowptr, csr, dis, b2, HB);

    // Layer 3
    k_gemm3<<<nbN, 256, 0, stream>>>(HB, W3, dis, t3);
    k_out<<<nbN, 256, 0, stream>>>(t3, rowptr, csr, dis, b3, out);
}